// Round 1
// baseline (5794.294 us; speedup 1.0000x reference)
//
#include <hip/hip_runtime.h>
#include <math.h>

#define NB 8
#define NP 2048
#define KNN 20
#define CSTR 520          // padded row stride of the cat feature buffer (floats)
#define NEG 0.2f

__device__ __forceinline__ float leaky(float x) { return x >= 0.0f ? x : NEG * x; }

// ---------------- transpose x (B,3,N) -> cat[:, :, 0:3] ----------------
__global__ void tx_kernel(const float* __restrict__ x, float* __restrict__ cat) {
    int i = blockIdx.x * blockDim.x + threadIdx.x;
    if (i >= NB * NP) return;
    int b = i / NP, n = i % NP;
    float* r = cat + (size_t)i * CSTR;
    r[0] = x[((size_t)b * 3 + 0) * NP + n];
    r[1] = x[((size_t)b * 3 + 1) * NP + n];
    r[2] = x[((size_t)b * 3 + 2) * NP + n];
}

// ---------------- W (O, C2) -> Wt (C2, O) ----------------
__global__ void transposeW(const float* __restrict__ W, float* __restrict__ Wt, int O, int C2) {
    int i = blockIdx.x * blockDim.x + threadIdx.x;
    if (i >= O * C2) return;
    int o = i / C2, c = i - o * C2;
    Wt[(size_t)c * O + o] = W[i];
}

// ---------------- squared norms of feature slice ----------------
__global__ void sqnorm_kernel(const float* __restrict__ cat, int off, int C, float* __restrict__ sq) {
    int i = blockIdx.x * blockDim.x + threadIdx.x;
    if (i >= NB * NP) return;
    const float* f = cat + (size_t)i * CSTR + off;
    float s = 0.f;
    for (int c = 0; c < C; ++c) s += f[c] * f[c];
    sq[i] = s;
}

// ---------------- KNN: one wave per query, top-20 via iterative argmax ----------------
__global__ __launch_bounds__(256) void knn_kernel(const float* __restrict__ cat, int off, int C,
                                                  const float* __restrict__ sq, int* __restrict__ idxout) {
    __shared__ float dist[4][NP];   // 32 KB
    __shared__ float qf[4][128];
    int wave = threadIdx.x >> 6, lane = threadIdx.x & 63;
    int q = blockIdx.x * 4 + wave;
    int b = q / NP, i = q - b * NP;
    const float* base = cat + (size_t)b * NP * CSTR + off;
    for (int c = lane; c < C; c += 64) qf[wave][c] = base[(size_t)i * CSTR + c];
    __syncthreads();
    float sqi = sq[q];
    for (int j = lane; j < NP; j += 64) {
        const float* fj = base + (size_t)j * CSTR;
        float dot = 0.f;
        for (int c = 0; c < C; ++c) dot += qf[wave][c] * fj[c];
        dist[wave][j] = 2.f * dot - sqi - sq[b * NP + j];
    }
    __syncthreads();
    int bj = lane * 32;   // each lane owns a contiguous chunk of 32 candidates
    for (int k = 0; k < KNN; ++k) {
        float bv = -INFINITY; int bi = 0x7fffffff;
        #pragma unroll
        for (int t = 0; t < 32; ++t) {
            float v = dist[wave][bj + t];
            if (v > bv) { bv = v; bi = bj + t; }    // strict > keeps lowest index on ties
        }
        for (int s = 32; s; s >>= 1) {
            float ov = __shfl_xor(bv, s);
            int oi = __shfl_xor(bi, s);
            if (ov > bv || (ov == bv && oi < bi)) { bv = ov; bi = oi; }
        }
        if (lane == 0) idxout[(size_t)q * KNN + k] = bi;
        if ((bi >> 5) == lane) dist[wave][bi] = -INFINITY;  // owner marks; re-read by same lane only
    }
}

// ---------------- edge conv: one point per block, blockDim == O ----------------
// h[o] = max_k leaky( (sum_c diff_k[c]*W[o,c] + sum_c ctr[c]*W[o,C+c]) * s[o] + b[o] )
__global__ void edgeconv_kernel(const float* __restrict__ cat, const int* __restrict__ idx,
                                const float* __restrict__ Wt, const float* __restrict__ g,
                                const float* __restrict__ bias, int Cin, int O, int outOff) {
    extern __shared__ float smem[];
    float* ctr = smem;
    float* difft = smem + ((Cin + 3) & ~3);   // [Cin][KNN] transposed, 16B-aligned rows (K=20 -> 80B)
    int p = blockIdx.x;
    int b = p / NP, n = p - b * NP;
    const float* rowb = cat + (size_t)b * NP * CSTR;
    int tid = threadIdx.x;
    for (int c = tid; c < Cin; c += blockDim.x) ctr[c] = rowb[(size_t)n * CSTR + c];
    __syncthreads();
    for (int e = tid; e < KNN * Cin; e += blockDim.x) {
        int k = e / Cin, c = e - k * Cin;
        int j = idx[(size_t)p * KNN + k];
        difft[c * KNN + k] = rowb[(size_t)j * CSTR + c] - ctr[c];
    }
    __syncthreads();
    int o = tid;   // blockDim.x == O
    const float bns = 1.0f / sqrtf(1.0f + 1e-5f);
    float s = g[o] * bns, bo = bias[o];
    float acc2 = 0.f;
    for (int c = 0; c < Cin; ++c) acc2 += ctr[c] * Wt[(size_t)(Cin + c) * O + o];
    float acck[KNN];
    #pragma unroll
    for (int k = 0; k < KNN; ++k) acck[k] = 0.f;
    for (int c = 0; c < Cin; ++c) {
        float w = Wt[(size_t)c * O + o];
        float dk[KNN];
        #pragma unroll
        for (int qd = 0; qd < 5; ++qd) {
            float4 v = *reinterpret_cast<const float4*>(difft + c * KNN + 4 * qd);
            dk[4*qd] = v.x; dk[4*qd+1] = v.y; dk[4*qd+2] = v.z; dk[4*qd+3] = v.w;
        }
        #pragma unroll
        for (int k = 0; k < KNN; ++k) acck[k] += dk[k] * w;
    }
    float hmax = -INFINITY;
    #pragma unroll
    for (int k = 0; k < KNN; ++k) hmax = fmaxf(hmax, leaky((acc2 + acck[k]) * s + bo));
    float* outp = const_cast<float*>(cat);   // disjoint columns: reads < Cin == outOff <= write col
    outp[((size_t)b * NP + n) * CSTR + outOff + o] = hmax;
}

// ---------------- fused W5 matmul + bn + leaky + partial max/sum pool over n ----------------
__global__ __launch_bounds__(256) void pool_w5_kernel(const float* __restrict__ cat, const float* __restrict__ W5t,
                                                      const float* __restrict__ g5, const float* __restrict__ b5,
                                                      float* __restrict__ pmax, float* __restrict__ psum) {
    __shared__ float rows[8][CSTR];   // 16.6 KB
    int blk = blockIdx.x;
    int nc = blk & 31; int rest = blk >> 5; int ot = rest & 3; int b = rest >> 2;
    int o = ot * 256 + threadIdx.x;
    const float bns = 1.0f / sqrtf(1.0f + 1e-5f);
    float s = g5[o] * bns, bo = b5[o];
    float vmax = -INFINITY, vsum = 0.f;
    for (int n0 = nc * 64; n0 < nc * 64 + 64; n0 += 8) {
        __syncthreads();
        for (int e = threadIdx.x; e < 8 * 515; e += 256) {
            int r = e / 515, c = e - r * 515;
            rows[r][c] = cat[((size_t)b * NP + n0 + r) * CSTR + c];
        }
        __syncthreads();
        for (int r = 0; r < 8; ++r) {
            float acc = 0.f;
            int c = 0;
            for (; c < 512; c += 4) {
                float4 rv = *reinterpret_cast<const float4*>(&rows[r][c]);
                acc += rv.x * W5t[(size_t)(c + 0) * 1024 + o];
                acc += rv.y * W5t[(size_t)(c + 1) * 1024 + o];
                acc += rv.z * W5t[(size_t)(c + 2) * 1024 + o];
                acc += rv.w * W5t[(size_t)(c + 3) * 1024 + o];
            }
            for (; c < 515; ++c) acc += rows[r][c] * W5t[(size_t)c * 1024 + o];
            float v = leaky(acc * s + bo);
            vmax = fmaxf(vmax, v); vsum += v;
        }
    }
    pmax[((size_t)b * 1024 + o) * 32 + nc] = vmax;
    psum[((size_t)b * 1024 + o) * 32 + nc] = vsum;
}

__global__ void pool_reduce_kernel(const float* __restrict__ pmax, const float* __restrict__ psum,
                                   float* __restrict__ f0) {
    int i = blockIdx.x * blockDim.x + threadIdx.x;
    if (i >= NB * 1024) return;
    int b = i >> 10, o = i & 1023;
    float m = -INFINITY, sm = 0.f;
    for (int nc = 0; nc < 32; ++nc) { m = fmaxf(m, pmax[(size_t)i * 32 + nc]); sm += psum[(size_t)i * 32 + nc]; }
    f0[(size_t)b * 2048 + o] = m;
    f0[(size_t)b * 2048 + 1024 + o] = sm * (1.0f / 2048.0f);
}

// ---------------- dense: one thread per (b, o) ----------------
__global__ void dense_kernel(const float* __restrict__ in, const float* __restrict__ W,
                             const float* __restrict__ bl, const float* __restrict__ g,
                             const float* __restrict__ bb, float* __restrict__ out,
                             int In, int Out, int act) {
    int i = blockIdx.x * blockDim.x + threadIdx.x;
    if (i >= NB * Out) return;
    int b = i / Out, o = i - b * Out;
    const float* w = W + (size_t)o * In;
    const float* xv = in + (size_t)b * In;
    float acc = 0.f;
    for (int c = 0; c < In; ++c) acc += xv[c] * w[c];
    acc += bl[o];
    if (act) {
        const float bns = 1.0f / sqrtf(1.0f + 1e-5f);
        acc = leaky(acc * (g[o] * bns) + bb[o]);
    }
    out[i] = acc;
}

extern "C" void kernel_launch(void* const* d_in, const int* in_sizes, int n_in,
                              void* d_out, int out_size, void* d_ws, size_t ws_size,
                              hipStream_t stream) {
    const float* x   = (const float*)d_in[0];
    const float* W1  = (const float*)d_in[2];
    const float* W2  = (const float*)d_in[3];
    const float* W3  = (const float*)d_in[4];
    const float* W4  = (const float*)d_in[5];
    const float* W5  = (const float*)d_in[6];
    const float* Wl1 = (const float*)d_in[7];
    const float* bl1 = (const float*)d_in[8];
    const float* Wl2 = (const float*)d_in[9];
    const float* bl2 = (const float*)d_in[10];
    const float* Wl3 = (const float*)d_in[11];
    const float* bl3 = (const float*)d_in[12];
    const float* g1 = (const float*)d_in[13]; const float* b1 = (const float*)d_in[14];
    const float* g2 = (const float*)d_in[15]; const float* b2 = (const float*)d_in[16];
    const float* g3 = (const float*)d_in[17]; const float* b3 = (const float*)d_in[18];
    const float* g4 = (const float*)d_in[19]; const float* b4 = (const float*)d_in[20];
    const float* g5 = (const float*)d_in[21]; const float* b5 = (const float*)d_in[22];
    const float* g6 = (const float*)d_in[23]; const float* bb6 = (const float*)d_in[24];
    const float* g7 = (const float*)d_in[25]; const float* bb7 = (const float*)d_in[26];

    float* ws = (float*)d_ws;
    size_t off = 0;
    float* CAT = ws + off; off += (size_t)NB * NP * CSTR;
    float* SQ  = ws + off; off += NB * NP;
    int*   IDX = (int*)(ws + off); off += (size_t)NB * NP * KNN;
    float* W1T = ws + off; off += 6 * 64;
    float* W2T = ws + off; off += 134 * 64;
    float* W3T = ws + off; off += 262 * 128;
    float* W4T = ws + off; off += 518 * 256;
    float* W5T = ws + off; off += 515 * 1024;
    float* PMAX = ws + off; off += (size_t)NB * 1024 * 32;
    float* PSUM = ws + off; off += (size_t)NB * 1024 * 32;
    float* F0 = ws + off; off += NB * 2048;
    float* F1 = ws + off; off += NB * 512;
    float* F2 = ws + off; off += NB * 256;
    (void)off; (void)ws_size; (void)in_sizes; (void)n_in; (void)out_size;

    dim3 b256(256);
    auto ec_smem = [](int Cin) { return (size_t)(((Cin + 3) & ~3) + Cin * KNN) * 4; };

    tx_kernel<<<(NB * NP + 255) / 256, b256, 0, stream>>>(x, CAT);
    transposeW<<<(64 * 6 + 255) / 256, b256, 0, stream>>>(W1, W1T, 64, 6);
    transposeW<<<(64 * 134 + 255) / 256, b256, 0, stream>>>(W2, W2T, 64, 134);
    transposeW<<<(128 * 262 + 255) / 256, b256, 0, stream>>>(W3, W3T, 128, 262);
    transposeW<<<(256 * 518 + 255) / 256, b256, 0, stream>>>(W4, W4T, 256, 518);
    transposeW<<<(1024 * 515 + 255) / 256, b256, 0, stream>>>(W5, W5T, 1024, 515);

    // layer 1: knn on xc (C=3), conv Cin=3 -> 64 at col 3
    sqnorm_kernel<<<(NB * NP + 255) / 256, b256, 0, stream>>>(CAT, 0, 3, SQ);
    knn_kernel<<<NB * NP / 4, b256, 0, stream>>>(CAT, 0, 3, SQ, IDX);
    edgeconv_kernel<<<NB * NP, 64, ec_smem(3), stream>>>(CAT, IDX, W1T, g1, b1, 3, 64, 3);
    // layer 2: knn on x1 (C=64 @ col 3), conv Cin=67 -> 64 at col 67
    sqnorm_kernel<<<(NB * NP + 255) / 256, b256, 0, stream>>>(CAT, 3, 64, SQ);
    knn_kernel<<<NB * NP / 4, b256, 0, stream>>>(CAT, 3, 64, SQ, IDX);
    edgeconv_kernel<<<NB * NP, 64, ec_smem(67), stream>>>(CAT, IDX, W2T, g2, b2, 67, 64, 67);
    // layer 3: knn on x2 (C=64 @ col 67), conv Cin=131 -> 128 at col 131
    sqnorm_kernel<<<(NB * NP + 255) / 256, b256, 0, stream>>>(CAT, 67, 64, SQ);
    knn_kernel<<<NB * NP / 4, b256, 0, stream>>>(CAT, 67, 64, SQ, IDX);
    edgeconv_kernel<<<NB * NP, 128, ec_smem(131), stream>>>(CAT, IDX, W3T, g3, b3, 131, 128, 131);
    // layer 4: knn on x3 (C=128 @ col 131), conv Cin=259 -> 256 at col 259
    sqnorm_kernel<<<(NB * NP + 255) / 256, b256, 0, stream>>>(CAT, 131, 128, SQ);
    knn_kernel<<<NB * NP / 4, b256, 0, stream>>>(CAT, 131, 128, SQ, IDX);
    edgeconv_kernel<<<NB * NP, 256, ec_smem(259), stream>>>(CAT, IDX, W4T, g4, b4, 259, 256, 259);

    // W5 + bn + leaky + global max/mean pool
    pool_w5_kernel<<<NB * 4 * 32, b256, 0, stream>>>(CAT, W5T, g5, b5, PMAX, PSUM);
    pool_reduce_kernel<<<(NB * 1024 + 255) / 256, b256, 0, stream>>>(PMAX, PSUM, F0);

    // MLP head
    dense_kernel<<<(NB * 512 + 255) / 256, b256, 0, stream>>>(F0, Wl1, bl1, g6, bb6, F1, 2048, 512, 1);
    dense_kernel<<<(NB * 256 + 255) / 256, b256, 0, stream>>>(F1, Wl2, bl2, g7, bb7, F2, 512, 256, 1);
    dense_kernel<<<(NB * 40 + 255) / 256, b256, 0, stream>>>(F2, Wl3, bl3, nullptr, nullptr,
                                                             (float*)d_out, 256, 40, 0);
}

// Round 2
// 5581.846 us; speedup vs baseline: 1.0381x; 1.0381x over previous
//
#include <hip/hip_runtime.h>
#include <math.h>

#define NB 8
#define NP 2048
#define KNN 20
#define CSTR 520          // padded row stride of the cat feature buffer (floats)
#define NEG 0.2f
// padded column layout: [x:0..3)[pad:3][x1:4..68)[x2:68..132)[x3:132..260)[x4:260..516)
// every slice start is a multiple of 4 floats (16B-aligned)

__device__ __forceinline__ float leaky(float x) { return x >= 0.0f ? x : NEG * x; }

// ---------------- transpose x (B,3,N) -> cat[:, :, 0:3], zero pad col 3 ----------------
__global__ void tx_kernel(const float* __restrict__ x, float* __restrict__ cat) {
    int i = blockIdx.x * blockDim.x + threadIdx.x;
    if (i >= NB * NP) return;
    int b = i / NP, n = i % NP;
    float* r = cat + (size_t)i * CSTR;
    r[0] = x[((size_t)b * 3 + 0) * NP + n];
    r[1] = x[((size_t)b * 3 + 1) * NP + n];
    r[2] = x[((size_t)b * 3 + 2) * NP + n];
    r[3] = 0.0f;
    // zero tail cols so pool_w5 staging reads defined values
    r[516] = 0.f; r[517] = 0.f; r[518] = 0.f; r[519] = 0.f;
}

// ---------------- conv weights W (O, 2*Cin) -> padded transposed Wt (2*PC, O) ----------------
// padded channel q -> real channel: q==3 -> zero row; q<3 -> q; q>3 -> q-1
__global__ void transposeWpad(const float* __restrict__ W, float* __restrict__ Wt,
                              int O, int Cin, int PC) {
    int i = blockIdx.x * blockDim.x + threadIdx.x;
    if (i >= O * 2 * PC) return;
    int p = i / O, o = i - p * O;
    int h = p / PC, q = p - h * PC;
    float v = 0.0f;
    if (q != 3) {
        int c = (q < 3) ? q : q - 1;
        if (c < Cin) v = W[(size_t)o * (2 * Cin) + h * Cin + c];
    }
    Wt[(size_t)p * O + o] = v;
}

// ---------------- W5 (1024, 515) -> padded transposed W5t (520, 1024) ----------------
__global__ void transposeW5(const float* __restrict__ W, float* __restrict__ Wt) {
    int i = blockIdx.x * blockDim.x + threadIdx.x;
    if (i >= 520 * 1024) return;
    int p = i >> 10, o = i & 1023;
    float v = 0.0f;
    if (p < 516 && p != 3) {
        int c = (p < 3) ? p : p - 1;
        v = W[(size_t)o * 515 + c];
    }
    Wt[i] = v;
}

// ---------------- squared norms of feature slice (padded C, pad col is zero) ----------------
__global__ void sqnorm_kernel(const float* __restrict__ cat, int off, int C, float* __restrict__ sq) {
    int i = blockIdx.x * blockDim.x + threadIdx.x;
    if (i >= NB * NP) return;
    const float* f = cat + (size_t)i * CSTR + off;
    float s = 0.f;
    for (int c = 0; c < C; c += 4) {
        float4 v = *reinterpret_cast<const float4*>(f + c);
        s += v.x * v.x + v.y * v.y + v.z * v.z + v.w * v.w;
    }
    sq[i] = s;
}

// ---------------- KNN v2: LDS-tiled distances + conflict-free selection ----------------
// block = 256 threads = 4 waves; one query per wave; 32 tiles of 64 candidates.
template <int C>
__global__ __launch_bounds__(256) void knn2_kernel(const float* __restrict__ cat, int off,
                                                   const float* __restrict__ sq,
                                                   int* __restrict__ idxout) {
    constexpr int CG = C / 4;
    __shared__ float4 tile[CG][65];     // padded -> conflict-free b128 read/write
    __shared__ float4 qf[4][CG];
    __shared__ float distL[4][NP];      // lane-strided ownership: dist[t*64+lane]
    int wave = threadIdx.x >> 6, lane = threadIdx.x & 63;
    int q = blockIdx.x * 4 + wave;
    int b = q >> 11, n = q & (NP - 1);
    const float* base = cat + (size_t)b * NP * CSTR + off;

    for (int cg = lane; cg < CG; cg += 64)
        qf[wave][cg] = *reinterpret_cast<const float4*>(base + (size_t)n * CSTR + 4 * cg);
    float sqi = sq[q];

    for (int t = 0; t < 32; ++t) {
        __syncthreads();
        // stage 64 candidate rows coalesced: consecutive threads -> consecutive 16B of a row
        for (int e = threadIdx.x; e < 64 * CG; e += 256) {
            int j = e / CG, cg = e - j * CG;
            tile[cg][j] = *reinterpret_cast<const float4*>(base + (size_t)(t * 64 + j) * CSTR + 4 * cg);
        }
        __syncthreads();
        float dot = 0.f;
        #pragma unroll
        for (int cg = 0; cg < CG; ++cg) {
            float4 a = qf[wave][cg];          // broadcast
            float4 v = tile[cg][lane];        // lane-consecutive 16B
            dot += a.x * v.x + a.y * v.y + a.z * v.z + a.w * v.w;
        }
        distL[wave][t * 64 + lane] = 2.f * dot - sqi - sq[b * NP + t * 64 + lane];
    }
    // selection: iterative argmax, lane owns j ≡ lane (mod 64) -> bank-conflict-free
    for (int k = 0; k < KNN; ++k) {
        float bv = -INFINITY; int bj = 0x7fffffff;
        #pragma unroll
        for (int t = 0; t < 32; ++t) {
            float v = distL[wave][t * 64 + lane];
            if (v > bv) { bv = v; bj = t * 64 + lane; }   // ascending j per lane; strict > keeps lowest
        }
        for (int s = 32; s; s >>= 1) {
            float ov = __shfl_xor(bv, s);
            int oj = __shfl_xor(bj, s);
            if (ov > bv || (ov == bv && oj < bj)) { bv = ov; bj = oj; }
        }
        if (lane == 0) idxout[(size_t)q * KNN + k] = bj;
        if ((bj & 63) == lane) distL[wave][bj] = -INFINITY;  // owner is sole reader of this slot
    }
}

// ---------------- edge conv: one point per block, blockDim == O ----------------
// padded input width PC (cols [0,PC)); Wt is (2*PC, O); writes out col range [PC, PC+O)... (outOff)
__global__ void edgeconv_kernel(const float* __restrict__ cat, const int* __restrict__ idx,
                                const float* __restrict__ Wt, const float* __restrict__ g,
                                const float* __restrict__ bias, int PC, int O, int outOff) {
    extern __shared__ float smem[];
    float* ctr = smem;
    float* difft = smem + ((PC + 3) & ~3);   // [PC][KNN] transposed
    int p = blockIdx.x;
    int b = p / NP, n = p - b * NP;
    const float* rowb = cat + (size_t)b * NP * CSTR;
    int tid = threadIdx.x;
    for (int c = tid; c < PC; c += blockDim.x) ctr[c] = rowb[(size_t)n * CSTR + c];
    __syncthreads();
    for (int e = tid; e < KNN * PC; e += blockDim.x) {
        int k = e / PC, c = e - k * PC;
        int j = idx[(size_t)p * KNN + k];
        difft[c * KNN + k] = rowb[(size_t)j * CSTR + c] - ctr[c];
    }
    __syncthreads();
    int o = tid;   // blockDim.x == O
    const float bns = 1.0f / sqrtf(1.0f + 1e-5f);
    float s = g[o] * bns, bo = bias[o];
    float acc2 = 0.f;
    for (int c = 0; c < PC; ++c) acc2 += ctr[c] * Wt[(size_t)(PC + c) * O + o];
    float acck[KNN];
    #pragma unroll
    for (int k = 0; k < KNN; ++k) acck[k] = 0.f;
    for (int c = 0; c < PC; ++c) {
        float w = Wt[(size_t)c * O + o];
        float dk[KNN];
        #pragma unroll
        for (int qd = 0; qd < 5; ++qd) {
            float4 v = *reinterpret_cast<const float4*>(difft + c * KNN + 4 * qd);
            dk[4*qd] = v.x; dk[4*qd+1] = v.y; dk[4*qd+2] = v.z; dk[4*qd+3] = v.w;
        }
        #pragma unroll
        for (int k = 0; k < KNN; ++k) acck[k] += dk[k] * w;
    }
    float hmax = -INFINITY;
    #pragma unroll
    for (int k = 0; k < KNN; ++k) hmax = fmaxf(hmax, leaky((acc2 + acck[k]) * s + bo));
    float* outp = const_cast<float*>(cat);   // reads cols < PC <= outOff: disjoint
    outp[((size_t)b * NP + n) * CSTR + outOff + o] = hmax;
}

// ---------------- fused W5 matmul + bn + leaky + partial max/sum pool over n ----------------
__global__ __launch_bounds__(256) void pool_w5_kernel(const float* __restrict__ cat, const float* __restrict__ W5t,
                                                      const float* __restrict__ g5, const float* __restrict__ b5,
                                                      float* __restrict__ pmax, float* __restrict__ psum) {
    __shared__ float rows[8][CSTR];   // 16.6 KB
    int blk = blockIdx.x;
    int nc = blk & 31; int rest = blk >> 5; int ot = rest & 3; int b = rest >> 2;
    int o = ot * 256 + threadIdx.x;
    const float bns = 1.0f / sqrtf(1.0f + 1e-5f);
    float s = g5[o] * bns, bo = b5[o];
    float vmax = -INFINITY, vsum = 0.f;
    for (int n0 = nc * 64; n0 < nc * 64 + 64; n0 += 8) {
        __syncthreads();
        for (int e = threadIdx.x; e < 8 * CSTR / 4; e += 256) {
            int r = e / (CSTR / 4), cg = e - r * (CSTR / 4);
            *reinterpret_cast<float4*>(&rows[r][4 * cg]) =
                *reinterpret_cast<const float4*>(&cat[((size_t)b * NP + n0 + r) * CSTR + 4 * cg]);
        }
        __syncthreads();
        for (int r = 0; r < 8; ++r) {
            float acc = 0.f;
            for (int c = 0; c < CSTR; c += 4) {
                float4 rv = *reinterpret_cast<const float4*>(&rows[r][c]);
                acc += rv.x * W5t[(size_t)(c + 0) * 1024 + o];
                acc += rv.y * W5t[(size_t)(c + 1) * 1024 + o];
                acc += rv.z * W5t[(size_t)(c + 2) * 1024 + o];
                acc += rv.w * W5t[(size_t)(c + 3) * 1024 + o];
            }
            float v = leaky(acc * s + bo);
            vmax = fmaxf(vmax, v); vsum += v;
        }
    }
    pmax[((size_t)b * 1024 + o) * 32 + nc] = vmax;
    psum[((size_t)b * 1024 + o) * 32 + nc] = vsum;
}

__global__ void pool_reduce_kernel(const float* __restrict__ pmax, const float* __restrict__ psum,
                                   float* __restrict__ f0) {
    int i = blockIdx.x * blockDim.x + threadIdx.x;
    if (i >= NB * 1024) return;
    int b = i >> 10, o = i & 1023;
    float m = -INFINITY, sm = 0.f;
    for (int nc = 0; nc < 32; ++nc) { m = fmaxf(m, pmax[(size_t)i * 32 + nc]); sm += psum[(size_t)i * 32 + nc]; }
    f0[(size_t)b * 2048 + o] = m;
    f0[(size_t)b * 2048 + 1024 + o] = sm * (1.0f / 2048.0f);
}

// ---------------- dense: one thread per (b, o) ----------------
__global__ void dense_kernel(const float* __restrict__ in, const float* __restrict__ W,
                             const float* __restrict__ bl, const float* __restrict__ g,
                             const float* __restrict__ bb, float* __restrict__ out,
                             int In, int Out, int act) {
    int i = blockIdx.x * blockDim.x + threadIdx.x;
    if (i >= NB * Out) return;
    int b = i / Out, o = i - b * Out;
    const float* w = W + (size_t)o * In;
    const float* xv = in + (size_t)b * In;
    float acc = 0.f;
    for (int c = 0; c < In; ++c) acc += xv[c] * w[c];
    acc += bl[o];
    if (act) {
        const float bns = 1.0f / sqrtf(1.0f + 1e-5f);
        acc = leaky(acc * (g[o] * bns) + bb[o]);
    }
    out[i] = acc;
}

extern "C" void kernel_launch(void* const* d_in, const int* in_sizes, int n_in,
                              void* d_out, int out_size, void* d_ws, size_t ws_size,
                              hipStream_t stream) {
    const float* x   = (const float*)d_in[0];
    const float* W1  = (const float*)d_in[2];
    const float* W2  = (const float*)d_in[3];
    const float* W3  = (const float*)d_in[4];
    const float* W4  = (const float*)d_in[5];
    const float* W5  = (const float*)d_in[6];
    const float* Wl1 = (const float*)d_in[7];
    const float* bl1 = (const float*)d_in[8];
    const float* Wl2 = (const float*)d_in[9];
    const float* bl2 = (const float*)d_in[10];
    const float* Wl3 = (const float*)d_in[11];
    const float* bl3 = (const float*)d_in[12];
    const float* g1 = (const float*)d_in[13]; const float* b1 = (const float*)d_in[14];
    const float* g2 = (const float*)d_in[15]; const float* b2 = (const float*)d_in[16];
    const float* g3 = (const float*)d_in[17]; const float* b3 = (const float*)d_in[18];
    const float* g4 = (const float*)d_in[19]; const float* b4 = (const float*)d_in[20];
    const float* g5 = (const float*)d_in[21]; const float* b5 = (const float*)d_in[22];
    const float* g6 = (const float*)d_in[23]; const float* bb6 = (const float*)d_in[24];
    const float* g7 = (const float*)d_in[25]; const float* bb7 = (const float*)d_in[26];

    float* ws = (float*)d_ws;
    size_t off = 0;
    float* CAT = ws + off; off += (size_t)NB * NP * CSTR;
    float* SQ  = ws + off; off += NB * NP;
    int*   IDX = (int*)(ws + off); off += (size_t)NB * NP * KNN;
    float* W1T = ws + off; off += 2 * 4 * 64;
    float* W2T = ws + off; off += 2 * 68 * 64;
    float* W3T = ws + off; off += 2 * 132 * 128;
    float* W4T = ws + off; off += 2 * 260 * 256;
    float* W5T = ws + off; off += 520 * 1024;
    float* PMAX = ws + off; off += (size_t)NB * 1024 * 32;
    float* PSUM = ws + off; off += (size_t)NB * 1024 * 32;
    float* F0 = ws + off; off += NB * 2048;
    float* F1 = ws + off; off += NB * 512;
    float* F2 = ws + off; off += NB * 256;
    (void)off; (void)ws_size; (void)in_sizes; (void)n_in; (void)out_size;

    dim3 b256(256);
    auto ec_smem = [](int PC) { return (size_t)(((PC + 3) & ~3) + PC * KNN) * 4; };

    tx_kernel<<<(NB * NP + 255) / 256, b256, 0, stream>>>(x, CAT);
    transposeWpad<<<(64 * 8 + 255) / 256, b256, 0, stream>>>(W1, W1T, 64, 3, 4);
    transposeWpad<<<(64 * 136 + 255) / 256, b256, 0, stream>>>(W2, W2T, 64, 67, 68);
    transposeWpad<<<(128 * 264 + 255) / 256, b256, 0, stream>>>(W3, W3T, 128, 131, 132);
    transposeWpad<<<(256 * 520 + 255) / 256, b256, 0, stream>>>(W4, W4T, 256, 259, 260);
    transposeW5<<<(520 * 1024 + 255) / 256, b256, 0, stream>>>(W5, W5T);

    // layer 1: knn on xc (padded C=4 @0), conv PC=4 -> 64 at col 4
    sqnorm_kernel<<<(NB * NP + 255) / 256, b256, 0, stream>>>(CAT, 0, 4, SQ);
    knn2_kernel<4><<<NB * NP / 4, b256, 0, stream>>>(CAT, 0, SQ, IDX);
    edgeconv_kernel<<<NB * NP, 64, ec_smem(4), stream>>>(CAT, IDX, W1T, g1, b1, 4, 64, 4);
    // layer 2: knn on x1 (C=64 @4), conv PC=68 -> 64 at col 68
    sqnorm_kernel<<<(NB * NP + 255) / 256, b256, 0, stream>>>(CAT, 4, 64, SQ);
    knn2_kernel<64><<<NB * NP / 4, b256, 0, stream>>>(CAT, 4, SQ, IDX);
    edgeconv_kernel<<<NB * NP, 64, ec_smem(68), stream>>>(CAT, IDX, W2T, g2, b2, 68, 64, 68);
    // layer 3: knn on x2 (C=64 @68), conv PC=132 -> 128 at col 132
    sqnorm_kernel<<<(NB * NP + 255) / 256, b256, 0, stream>>>(CAT, 68, 64, SQ);
    knn2_kernel<64><<<NB * NP / 4, b256, 0, stream>>>(CAT, 68, SQ, IDX);
    edgeconv_kernel<<<NB * NP, 128, ec_smem(132), stream>>>(CAT, IDX, W3T, g3, b3, 132, 128, 132);
    // layer 4: knn on x3 (C=128 @132), conv PC=260 -> 256 at col 260
    sqnorm_kernel<<<(NB * NP + 255) / 256, b256, 0, stream>>>(CAT, 132, 128, SQ);
    knn2_kernel<128><<<NB * NP / 4, b256, 0, stream>>>(CAT, 132, SQ, IDX);
    edgeconv_kernel<<<NB * NP, 256, ec_smem(260), stream>>>(CAT, IDX, W4T, g4, b4, 260, 256, 260);

    // W5 + bn + leaky + global max/mean pool
    pool_w5_kernel<<<NB * 4 * 32, b256, 0, stream>>>(CAT, W5T, g5, b5, PMAX, PSUM);
    pool_reduce_kernel<<<(NB * 1024 + 255) / 256, b256, 0, stream>>>(PMAX, PSUM, F0);

    // MLP head
    dense_kernel<<<(NB * 512 + 255) / 256, b256, 0, stream>>>(F0, Wl1, bl1, g6, bb6, F1, 2048, 512, 1);
    dense_kernel<<<(NB * 256 + 255) / 256, b256, 0, stream>>>(F1, Wl2, bl2, g7, bb7, F2, 512, 256, 1);
    dense_kernel<<<(NB * 40 + 255) / 256, b256, 0, stream>>>(F2, Wl3, bl3, nullptr, nullptr,
                                                             (float*)d_out, 256, 40, 0);
}

// Round 3
// 3771.752 us; speedup vs baseline: 1.5362x; 1.4799x over previous
//
#include <hip/hip_runtime.h>
#include <math.h>

#define NB 8
#define NP 2048
#define KNN 20
#define CSTR 520          // padded row stride of the cat feature buffer (floats)
#define NEG 0.2f
// padded column layout: [x:0..3)[pad:3][x1:4..68)[x2:68..132)[x3:132..260)[x4:260..516)
// every slice start is a multiple of 4 floats (16B-aligned)

__device__ __forceinline__ float leaky(float x) { return x >= 0.0f ? x : NEG * x; }

// ---------------- transpose x (B,3,N) -> cat[:, :, 0:3], zero pad col 3 ----------------
__global__ void tx_kernel(const float* __restrict__ x, float* __restrict__ cat) {
    int i = blockIdx.x * blockDim.x + threadIdx.x;
    if (i >= NB * NP) return;
    int b = i / NP, n = i % NP;
    float* r = cat + (size_t)i * CSTR;
    r[0] = x[((size_t)b * 3 + 0) * NP + n];
    r[1] = x[((size_t)b * 3 + 1) * NP + n];
    r[2] = x[((size_t)b * 3 + 2) * NP + n];
    r[3] = 0.0f;
    // zero tail cols so pool_w5 staging reads defined values
    r[516] = 0.f; r[517] = 0.f; r[518] = 0.f; r[519] = 0.f;
}

// ---------------- conv weights W (O, 2*Cin) -> padded transposed Wt (2*PC, O) ----------------
// padded channel q -> real channel: q==3 -> zero row; q<3 -> q; q>3 -> q-1
__global__ void transposeWpad(const float* __restrict__ W, float* __restrict__ Wt,
                              int O, int Cin, int PC) {
    int i = blockIdx.x * blockDim.x + threadIdx.x;
    if (i >= O * 2 * PC) return;
    int p = i / O, o = i - p * O;
    int h = p / PC, q = p - h * PC;
    float v = 0.0f;
    if (q != 3) {
        int c = (q < 3) ? q : q - 1;
        if (c < Cin) v = W[(size_t)o * (2 * Cin) + h * Cin + c];
    }
    Wt[(size_t)p * O + o] = v;
}

// ---------------- W5 (1024, 515) -> padded transposed W5t (520, 1024) ----------------
__global__ void transposeW5(const float* __restrict__ W, float* __restrict__ Wt) {
    int i = blockIdx.x * blockDim.x + threadIdx.x;
    if (i >= 520 * 1024) return;
    int p = i >> 10, o = i & 1023;
    float v = 0.0f;
    if (p < 516 && p != 3) {
        int c = (p < 3) ? p : p - 1;
        v = W[(size_t)o * 515 + c];
    }
    Wt[i] = v;
}

// ---------------- squared norms of feature slice (padded C, pad col is zero) ----------------
__global__ void sqnorm_kernel(const float* __restrict__ cat, int off, int C, float* __restrict__ sq) {
    int i = blockIdx.x * blockDim.x + threadIdx.x;
    if (i >= NB * NP) return;
    const float* f = cat + (size_t)i * CSTR + off;
    float s = 0.f;
    for (int c = 0; c < C; c += 4) {
        float4 v = *reinterpret_cast<const float4*>(f + c);
        s += v.x * v.x + v.y * v.y + v.z * v.z + v.w * v.w;
    }
    sq[i] = s;
}

// ---------------- KNN v2: LDS-tiled distances + conflict-free selection ----------------
// block = 256 threads = 4 waves; one query per wave; 32 tiles of 64 candidates.
template <int C>
__global__ __launch_bounds__(256) void knn2_kernel(const float* __restrict__ cat, int off,
                                                   const float* __restrict__ sq,
                                                   int* __restrict__ idxout) {
    constexpr int CG = C / 4;
    __shared__ float4 tile[CG][65];     // padded -> conflict-free b128 read/write
    __shared__ float4 qf[4][CG];
    __shared__ float distL[4][NP];      // lane-strided ownership: dist[t*64+lane]
    int wave = threadIdx.x >> 6, lane = threadIdx.x & 63;
    int q = blockIdx.x * 4 + wave;
    int b = q >> 11, n = q & (NP - 1);
    const float* base = cat + (size_t)b * NP * CSTR + off;

    for (int cg = lane; cg < CG; cg += 64)
        qf[wave][cg] = *reinterpret_cast<const float4*>(base + (size_t)n * CSTR + 4 * cg);
    float sqi = sq[q];

    for (int t = 0; t < 32; ++t) {
        __syncthreads();
        // stage 64 candidate rows coalesced: consecutive threads -> consecutive 16B of a row
        for (int e = threadIdx.x; e < 64 * CG; e += 256) {
            int j = e / CG, cg = e - j * CG;
            tile[cg][j] = *reinterpret_cast<const float4*>(base + (size_t)(t * 64 + j) * CSTR + 4 * cg);
        }
        __syncthreads();
        float dot = 0.f;
        #pragma unroll
        for (int cg = 0; cg < CG; ++cg) {
            float4 a = qf[wave][cg];          // broadcast
            float4 v = tile[cg][lane];        // lane-consecutive 16B
            dot += a.x * v.x + a.y * v.y + a.z * v.z + a.w * v.w;
        }
        distL[wave][t * 64 + lane] = 2.f * dot - sqi - sq[b * NP + t * 64 + lane];
    }
    // selection: iterative argmax, lane owns j ≡ lane (mod 64) -> bank-conflict-free
    for (int k = 0; k < KNN; ++k) {
        float bv = -INFINITY; int bj = 0x7fffffff;
        #pragma unroll
        for (int t = 0; t < 32; ++t) {
            float v = distL[wave][t * 64 + lane];
            if (v > bv) { bv = v; bj = t * 64 + lane; }   // ascending j per lane; strict > keeps lowest
        }
        for (int s = 32; s; s >>= 1) {
            float ov = __shfl_xor(bv, s);
            int oj = __shfl_xor(bj, s);
            if (ov > bv || (ov == bv && oj < bj)) { bv = ov; bj = oj; }
        }
        if (lane == 0) idxout[(size_t)q * KNN + k] = bj;
        if ((bj & 63) == lane) distL[wave][bj] = -INFINITY;  // owner is sole reader of this slot
    }
}

// ---------------- edge conv: one point per block, blockDim == O ----------------
// padded input width PC (cols [0,PC)); Wt is (2*PC, O); writes out col range [outOff, outOff+O)
__global__ void edgeconv_kernel(const float* __restrict__ cat, const int* __restrict__ idx,
                                const float* __restrict__ Wt, const float* __restrict__ g,
                                const float* __restrict__ bias, int PC, int O, int outOff) {
    extern __shared__ float smem[];
    float* ctr = smem;
    float* difft = smem + ((PC + 3) & ~3);   // [PC][KNN] transposed
    int p = blockIdx.x;
    int b = p / NP, n = p - b * NP;
    const float* rowb = cat + (size_t)b * NP * CSTR;
    int tid = threadIdx.x;
    for (int c = tid; c < PC; c += blockDim.x) ctr[c] = rowb[(size_t)n * CSTR + c];
    __syncthreads();
    for (int e = tid; e < KNN * PC; e += blockDim.x) {
        int k = e / PC, c = e - k * PC;
        int j = idx[(size_t)p * KNN + k];
        difft[c * KNN + k] = rowb[(size_t)j * CSTR + c] - ctr[c];
    }
    __syncthreads();
    int o = tid;   // blockDim.x == O
    const float bns = 1.0f / sqrtf(1.0f + 1e-5f);
    float s = g[o] * bns, bo = bias[o];
    float acc2 = 0.f;
    for (int c = 0; c < PC; ++c) acc2 += ctr[c] * Wt[(size_t)(PC + c) * O + o];
    float acck[KNN];
    #pragma unroll
    for (int k = 0; k < KNN; ++k) acck[k] = 0.f;
    for (int c = 0; c < PC; ++c) {
        float w = Wt[(size_t)c * O + o];
        float dk[KNN];
        #pragma unroll
        for (int qd = 0; qd < 5; ++qd) {
            float4 v = *reinterpret_cast<const float4*>(difft + c * KNN + 4 * qd);
            dk[4*qd] = v.x; dk[4*qd+1] = v.y; dk[4*qd+2] = v.z; dk[4*qd+3] = v.w;
        }
        #pragma unroll
        for (int k = 0; k < KNN; ++k) acck[k] += dk[k] * w;
    }
    float hmax = -INFINITY;
    #pragma unroll
    for (int k = 0; k < KNN; ++k) hmax = fmaxf(hmax, leaky((acc2 + acck[k]) * s + bo));
    float* outp = const_cast<float*>(cat);   // reads cols < PC <= outOff: disjoint
    outp[((size_t)b * NP + n) * CSTR + outOff + o] = hmax;
}

// ---------------- fused W5 matmul + bn + leaky + partial max/sum pool over n ----------------
// v2: 16-row register blocking -> 16 FMAs per W5t global load (was 1).
#define RSTAGE 16
__global__ __launch_bounds__(256) void pool_w5_kernel(const float* __restrict__ cat, const float* __restrict__ W5t,
                                                      const float* __restrict__ g5, const float* __restrict__ b5,
                                                      float* __restrict__ pmax, float* __restrict__ psum) {
    __shared__ float rows[RSTAGE][CSTR];   // 33.3 KB
    int blk = blockIdx.x;
    int nc = blk & 31; int rest = blk >> 5; int ot = rest & 3; int b = rest >> 2;
    int o = ot * 256 + threadIdx.x;
    const float bns = 1.0f / sqrtf(1.0f + 1e-5f);
    float s = g5[o] * bns, bo = b5[o];
    float vmax = -INFINITY, vsum = 0.f;
    for (int n0 = nc * 64; n0 < nc * 64 + 64; n0 += RSTAGE) {
        __syncthreads();
        for (int e = threadIdx.x; e < RSTAGE * (CSTR / 4); e += 256) {
            int r = e / (CSTR / 4), cg = e - r * (CSTR / 4);
            *reinterpret_cast<float4*>(&rows[r][4 * cg]) =
                *reinterpret_cast<const float4*>(&cat[((size_t)b * NP + n0 + r) * CSTR + 4 * cg]);
        }
        __syncthreads();
        float acc[RSTAGE];
        #pragma unroll
        for (int r = 0; r < RSTAGE; ++r) acc[r] = 0.f;
        for (int c = 0; c < CSTR; c += 4) {
            float w0 = W5t[(size_t)(c + 0) * 1024 + o];
            float w1 = W5t[(size_t)(c + 1) * 1024 + o];
            float w2 = W5t[(size_t)(c + 2) * 1024 + o];
            float w3 = W5t[(size_t)(c + 3) * 1024 + o];
            #pragma unroll
            for (int r = 0; r < RSTAGE; ++r) {
                float4 rv = *reinterpret_cast<const float4*>(&rows[r][c]);
                acc[r] += rv.x * w0 + rv.y * w1 + rv.z * w2 + rv.w * w3;
            }
        }
        #pragma unroll
        for (int r = 0; r < RSTAGE; ++r) {
            float v = leaky(acc[r] * s + bo);
            vmax = fmaxf(vmax, v); vsum += v;
        }
    }
    pmax[((size_t)b * 1024 + o) * 32 + nc] = vmax;
    psum[((size_t)b * 1024 + o) * 32 + nc] = vsum;
}

__global__ void pool_reduce_kernel(const float* __restrict__ pmax, const float* __restrict__ psum,
                                   float* __restrict__ f0) {
    int i = blockIdx.x * blockDim.x + threadIdx.x;
    if (i >= NB * 1024) return;
    int b = i >> 10, o = i & 1023;
    float m = -INFINITY, sm = 0.f;
    for (int nc = 0; nc < 32; ++nc) { m = fmaxf(m, pmax[(size_t)i * 32 + nc]); sm += psum[(size_t)i * 32 + nc]; }
    f0[(size_t)b * 2048 + o] = m;
    f0[(size_t)b * 2048 + 1024 + o] = sm * (1.0f / 2048.0f);
}

// ---------------- dense: one thread per (b, o) ----------------
__global__ void dense_kernel(const float* __restrict__ in, const float* __restrict__ W,
                             const float* __restrict__ bl, const float* __restrict__ g,
                             const float* __restrict__ bb, float* __restrict__ out,
                             int In, int Out, int act) {
    int i = blockIdx.x * blockDim.x + threadIdx.x;
    if (i >= NB * Out) return;
    int b = i / Out, o = i - b * Out;
    const float* w = W + (size_t)o * In;
    const float* xv = in + (size_t)b * In;
    float acc = 0.f;
    for (int c = 0; c < In; ++c) acc += xv[c] * w[c];
    acc += bl[o];
    if (act) {
        const float bns = 1.0f / sqrtf(1.0f + 1e-5f);
        acc = leaky(acc * (g[o] * bns) + bb[o]);
    }
    out[i] = acc;
}

extern "C" void kernel_launch(void* const* d_in, const int* in_sizes, int n_in,
                              void* d_out, int out_size, void* d_ws, size_t ws_size,
                              hipStream_t stream) {
    const float* x   = (const float*)d_in[0];
    const float* W1  = (const float*)d_in[2];
    const float* W2  = (const float*)d_in[3];
    const float* W3  = (const float*)d_in[4];
    const float* W4  = (const float*)d_in[5];
    const float* W5  = (const float*)d_in[6];
    const float* Wl1 = (const float*)d_in[7];
    const float* bl1 = (const float*)d_in[8];
    const float* Wl2 = (const float*)d_in[9];
    const float* bl2 = (const float*)d_in[10];
    const float* Wl3 = (const float*)d_in[11];
    const float* bl3 = (const float*)d_in[12];
    const float* g1 = (const float*)d_in[13]; const float* b1 = (const float*)d_in[14];
    const float* g2 = (const float*)d_in[15]; const float* b2 = (const float*)d_in[16];
    const float* g3 = (const float*)d_in[17]; const float* b3 = (const float*)d_in[18];
    const float* g4 = (const float*)d_in[19]; const float* b4 = (const float*)d_in[20];
    const float* g5 = (const float*)d_in[21]; const float* b5 = (const float*)d_in[22];
    const float* g6 = (const float*)d_in[23]; const float* bb6 = (const float*)d_in[24];
    const float* g7 = (const float*)d_in[25]; const float* bb7 = (const float*)d_in[26];

    float* ws = (float*)d_ws;
    size_t off = 0;
    float* CAT = ws + off; off += (size_t)NB * NP * CSTR;
    float* SQ  = ws + off; off += NB * NP;
    int*   IDX = (int*)(ws + off); off += (size_t)NB * NP * KNN;
    float* W1T = ws + off; off += 2 * 4 * 64;
    float* W2T = ws + off; off += 2 * 68 * 64;
    float* W3T = ws + off; off += 2 * 132 * 128;
    float* W4T = ws + off; off += 2 * 260 * 256;
    float* W5T = ws + off; off += 520 * 1024;
    float* PMAX = ws + off; off += (size_t)NB * 1024 * 32;
    float* PSUM = ws + off; off += (size_t)NB * 1024 * 32;
    float* F0 = ws + off; off += NB * 2048;
    float* F1 = ws + off; off += NB * 512;
    float* F2 = ws + off; off += NB * 256;
    (void)off; (void)ws_size; (void)in_sizes; (void)n_in; (void)out_size;

    dim3 b256(256);
    auto ec_smem = [](int PC) { return (size_t)(((PC + 3) & ~3) + PC * KNN) * 4; };

    tx_kernel<<<(NB * NP + 255) / 256, b256, 0, stream>>>(x, CAT);
    transposeWpad<<<(64 * 8 + 255) / 256, b256, 0, stream>>>(W1, W1T, 64, 3, 4);
    transposeWpad<<<(64 * 136 + 255) / 256, b256, 0, stream>>>(W2, W2T, 64, 67, 68);
    transposeWpad<<<(128 * 264 + 255) / 256, b256, 0, stream>>>(W3, W3T, 128, 131, 132);
    transposeWpad<<<(256 * 520 + 255) / 256, b256, 0, stream>>>(W4, W4T, 256, 259, 260);
    transposeW5<<<(520 * 1024 + 255) / 256, b256, 0, stream>>>(W5, W5T);

    // layer 1: knn on xc (padded C=4 @0), conv PC=4 -> 64 at col 4
    sqnorm_kernel<<<(NB * NP + 255) / 256, b256, 0, stream>>>(CAT, 0, 4, SQ);
    knn2_kernel<4><<<NB * NP / 4, b256, 0, stream>>>(CAT, 0, SQ, IDX);
    edgeconv_kernel<<<NB * NP, 64, ec_smem(4), stream>>>(CAT, IDX, W1T, g1, b1, 4, 64, 4);
    // layer 2: knn on x1 (C=64 @4), conv PC=68 -> 64 at col 68
    sqnorm_kernel<<<(NB * NP + 255) / 256, b256, 0, stream>>>(CAT, 4, 64, SQ);
    knn2_kernel<64><<<NB * NP / 4, b256, 0, stream>>>(CAT, 4, SQ, IDX);
    edgeconv_kernel<<<NB * NP, 64, ec_smem(68), stream>>>(CAT, IDX, W2T, g2, b2, 68, 64, 68);
    // layer 3: knn on x2 (C=64 @68), conv PC=132 -> 128 at col 132
    sqnorm_kernel<<<(NB * NP + 255) / 256, b256, 0, stream>>>(CAT, 68, 64, SQ);
    knn2_kernel<64><<<NB * NP / 4, b256, 0, stream>>>(CAT, 68, SQ, IDX);
    edgeconv_kernel<<<NB * NP, 128, ec_smem(132), stream>>>(CAT, IDX, W3T, g3, b3, 132, 128, 132);
    // layer 4: knn on x3 (C=128 @132), conv PC=260 -> 256 at col 260
    sqnorm_kernel<<<(NB * NP + 255) / 256, b256, 0, stream>>>(CAT, 132, 128, SQ);
    knn2_kernel<128><<<NB * NP / 4, b256, 0, stream>>>(CAT, 132, SQ, IDX);
    edgeconv_kernel<<<NB * NP, 256, ec_smem(260), stream>>>(CAT, IDX, W4T, g4, b4, 260, 256, 260);

    // W5 + bn + leaky + global max/mean pool
    pool_w5_kernel<<<NB * 4 * 32, b256, 0, stream>>>(CAT, W5T, g5, b5, PMAX, PSUM);
    pool_reduce_kernel<<<(NB * 1024 + 255) / 256, b256, 0, stream>>>(PMAX, PSUM, F0);

    // MLP head
    dense_kernel<<<(NB * 512 + 255) / 256, b256, 0, stream>>>(F0, Wl1, bl1, g6, bb6, F1, 2048, 512, 1);
    dense_kernel<<<(NB * 256 + 255) / 256, b256, 0, stream>>>(F1, Wl2, bl2, g7, bb7, F2, 512, 256, 1);
    dense_kernel<<<(NB * 40 + 255) / 256, b256, 0, stream>>>(F2, Wl3, bl3, nullptr, nullptr,
                                                             (float*)d_out, 256, 40, 0);
}

// Round 5
// 2857.401 us; speedup vs baseline: 2.0278x; 1.3200x over previous
//
#include <hip/hip_runtime.h>
#include <math.h>

#define NB 8
#define NP 2048
#define KNN 20
#define CSTR 520          // padded row stride of the cat feature buffer (floats)
#define NEG 0.2f
// padded column layout: [x:0..3)[pad:3][x1:4..68)[x2:68..132)[x3:132..260)[x4:260..516)
// every slice start is a multiple of 4 floats (16B-aligned)

__device__ __forceinline__ float leaky(float x) { return x >= 0.0f ? x : NEG * x; }

// ---------------- transpose x (B,3,N) -> cat[:, :, 0:3], zero pad col 3 ----------------
__global__ void tx_kernel(const float* __restrict__ x, float* __restrict__ cat) {
    int i = blockIdx.x * blockDim.x + threadIdx.x;
    if (i >= NB * NP) return;
    int b = i / NP, n = i % NP;
    float* r = cat + (size_t)i * CSTR;
    r[0] = x[((size_t)b * 3 + 0) * NP + n];
    r[1] = x[((size_t)b * 3 + 1) * NP + n];
    r[2] = x[((size_t)b * 3 + 2) * NP + n];
    r[3] = 0.0f;
    r[516] = 0.f; r[517] = 0.f; r[518] = 0.f; r[519] = 0.f;
}

// ---------------- conv weights W (O, 2*Cin) -> Wyz (PC, 2*O): [Wd | Wc - Wd] ----------------
// padded channel q: q==3 -> zero row; q<3 -> c=q; q>3 -> c=q-1  (slice always starts at col 0)
__global__ void buildWyz(const float* __restrict__ W, float* __restrict__ Wyz,
                         int O, int Cin, int PC) {
    int i = blockIdx.x * blockDim.x + threadIdx.x;
    int N2 = 2 * O;
    if (i >= PC * N2) return;
    int q = i / N2, n = i - q * N2;
    float v = 0.0f;
    if (q != 3) {
        int c = (q < 3) ? q : q - 1;
        if (c < Cin) {
            int o = (n < O) ? n : n - O;
            float wd = W[(size_t)o * (2 * Cin) + c];
            v = (n < O) ? wd : (W[(size_t)o * (2 * Cin) + Cin + c] - wd);
        }
    }
    Wyz[i] = v;
}

// ---------------- W5 (1024, 515) -> padded transposed W5t (520, 1024) ----------------
__global__ void transposeW5(const float* __restrict__ W, float* __restrict__ Wt) {
    int i = blockIdx.x * blockDim.x + threadIdx.x;
    if (i >= 520 * 1024) return;
    int p = i >> 10, o = i & 1023;
    float v = 0.0f;
    if (p < 516 && p != 3) {
        int c = (p < 3) ? p : p - 1;
        v = W[(size_t)o * 515 + c];
    }
    Wt[i] = v;
}

// ---------------- squared norms of feature slice (padded C, pad col is zero) ----------------
__global__ void sqnorm_kernel(const float* __restrict__ cat, int off, int C, float* __restrict__ sq) {
    int i = blockIdx.x * blockDim.x + threadIdx.x;
    if (i >= NB * NP) return;
    const float* f = cat + (size_t)i * CSTR + off;
    float s = 0.f;
    for (int c = 0; c < C; c += 4) {
        float4 v = *reinterpret_cast<const float4*>(f + c);
        s += v.x * v.x + v.y * v.y + v.z * v.z + v.w * v.w;
    }
    sq[i] = s;
}

// ---------------- KNN v2: LDS-tiled distances + conflict-free selection ----------------
template <int C>
__global__ __launch_bounds__(256) void knn2_kernel(const float* __restrict__ cat, int off,
                                                   const float* __restrict__ sq,
                                                   int* __restrict__ idxout) {
    constexpr int CG = C / 4;
    __shared__ float4 tile[CG][65];
    __shared__ float4 qf[4][CG];
    __shared__ float distL[4][NP];      // lane-strided ownership: dist[t*64+lane]
    int wave = threadIdx.x >> 6, lane = threadIdx.x & 63;
    int q = blockIdx.x * 4 + wave;
    int b = q >> 11, n = q & (NP - 1);
    const float* base = cat + (size_t)b * NP * CSTR + off;

    for (int cg = lane; cg < CG; cg += 64)
        qf[wave][cg] = *reinterpret_cast<const float4*>(base + (size_t)n * CSTR + 4 * cg);
    float sqi = sq[q];

    for (int t = 0; t < 32; ++t) {
        __syncthreads();
        for (int e = threadIdx.x; e < 64 * CG; e += 256) {
            int j = e / CG, cg = e - j * CG;
            tile[cg][j] = *reinterpret_cast<const float4*>(base + (size_t)(t * 64 + j) * CSTR + 4 * cg);
        }
        __syncthreads();
        float dot = 0.f;
        #pragma unroll
        for (int cg = 0; cg < CG; ++cg) {
            float4 a = qf[wave][cg];
            float4 v = tile[cg][lane];
            dot += a.x * v.x + a.y * v.y + a.z * v.z + a.w * v.w;
        }
        distL[wave][t * 64 + lane] = 2.f * dot - sqi - sq[b * NP + t * 64 + lane];
    }
    for (int k = 0; k < KNN; ++k) {
        float bv = -INFINITY; int bj = 0x7fffffff;
        #pragma unroll
        for (int t = 0; t < 32; ++t) {
            float v = distL[wave][t * 64 + lane];
            if (v > bv) { bv = v; bj = t * 64 + lane; }
        }
        for (int s = 32; s; s >>= 1) {
            float ov = __shfl_xor(bv, s);
            int oj = __shfl_xor(bj, s);
            if (ov > bv || (ov == bv && oj < bj)) { bv = ov; bj = oj; }
        }
        if (lane == 0) idxout[(size_t)q * KNN + k] = bj;
        if ((bj & 63) == lane) distL[wave][bj] = -INFINITY;
    }
}

// ---------------- YZ GEMM: YZ[p][:] = cat[p][0:K] @ Wyz (K x N2) ----------------
// 16-row register blocking (pool_w5 pattern): 16 FMAs per W load, LDS broadcast reads.
template <int K, int NT>
__global__ __launch_bounds__(NT) void gemm_yz_kernel(const float* __restrict__ cat, int off,
                                                     const float* __restrict__ W, int N2,
                                                     float* __restrict__ YZ) {
    __shared__ float rows[16][K];
    int col = blockIdx.y * NT + threadIdx.x;
    const float* src = cat + (size_t)blockIdx.x * 16 * CSTR + off;
    for (int e = threadIdx.x; e < 16 * (K / 4); e += NT) {
        int r = e / (K / 4), cg = e - r * (K / 4);
        *reinterpret_cast<float4*>(&rows[r][4 * cg]) =
            *reinterpret_cast<const float4*>(src + (size_t)r * CSTR + 4 * cg);
    }
    __syncthreads();
    float acc[16];
    #pragma unroll
    for (int r = 0; r < 16; ++r) acc[r] = 0.f;
    for (int c = 0; c < K; c += 4) {
        float w0 = W[(size_t)(c + 0) * N2 + col];
        float w1 = W[(size_t)(c + 1) * N2 + col];
        float w2 = W[(size_t)(c + 2) * N2 + col];
        float w3 = W[(size_t)(c + 3) * N2 + col];
        #pragma unroll
        for (int r = 0; r < 16; ++r) {
            float4 rv = *reinterpret_cast<const float4*>(&rows[r][c]);
            acc[r] += rv.x * w0 + rv.y * w1 + rv.z * w2 + rv.w * w3;
        }
    }
    float* dst = YZ + (size_t)blockIdx.x * 16 * N2 + col;
    #pragma unroll
    for (int r = 0; r < 16; ++r) dst[(size_t)r * N2] = acc[r];
}

// ---------------- combine: out[p][o] = max_k leaky((Y[j_k][o] + Z[p][o])*s + b) ----------------
template <int O>
__global__ __launch_bounds__(256) void combine_kernel(const float* __restrict__ YZ, int N2,
                                                      const int* __restrict__ idx,
                                                      const float* __restrict__ g,
                                                      const float* __restrict__ bias,
                                                      float* __restrict__ cat, int outOff) {
    constexpr int PPB = 256 / O;
    int sub = threadIdx.x / O, o = threadIdx.x % O;
    int p = blockIdx.x * PPB + sub;
    int bbase = p & ~(NP - 1);             // batch-global row base for local neighbor ids
    const float bns = 1.0f / sqrtf(1.0f + 1e-5f);
    float s = g[o] * bns, bo = bias[o];
    float z = YZ[(size_t)p * N2 + O + o];
    int js[KNN];
    #pragma unroll
    for (int k = 0; k < KNN; ++k) js[k] = idx[(size_t)p * KNN + k];
    float m = -INFINITY;
    #pragma unroll
    for (int k = 0; k < KNN; ++k) {
        float y = YZ[(size_t)(bbase + js[k]) * N2 + o];
        m = fmaxf(m, leaky((y + z) * s + bo));
    }
    cat[(size_t)p * CSTR + outOff + o] = m;
}

// ---------------- fused W5 matmul + bn + leaky + partial max/sum pool over n ----------------
#define RSTAGE 16
__global__ __launch_bounds__(256) void pool_w5_kernel(const float* __restrict__ cat, const float* __restrict__ W5t,
                                                      const float* __restrict__ g5, const float* __restrict__ b5,
                                                      float* __restrict__ pmax, float* __restrict__ psum) {
    __shared__ float rows[RSTAGE][CSTR];   // 33.3 KB
    int blk = blockIdx.x;
    int nc = blk & 31; int rest = blk >> 5; int ot = rest & 3; int b = rest >> 2;
    int o = ot * 256 + threadIdx.x;
    const float bns = 1.0f / sqrtf(1.0f + 1e-5f);
    float s = g5[o] * bns, bo = b5[o];
    float vmax = -INFINITY, vsum = 0.f;
    for (int n0 = nc * 64; n0 < nc * 64 + 64; n0 += RSTAGE) {
        __syncthreads();
        for (int e = threadIdx.x; e < RSTAGE * (CSTR / 4); e += 256) {
            int r = e / (CSTR / 4), cg = e - r * (CSTR / 4);
            *reinterpret_cast<float4*>(&rows[r][4 * cg]) =
                *reinterpret_cast<const float4*>(&cat[((size_t)b * NP + n0 + r) * CSTR + 4 * cg]);
        }
        __syncthreads();
        float acc[RSTAGE];
        #pragma unroll
        for (int r = 0; r < RSTAGE; ++r) acc[r] = 0.f;
        for (int c = 0; c < CSTR; c += 4) {
            float w0 = W5t[(size_t)(c + 0) * 1024 + o];
            float w1 = W5t[(size_t)(c + 1) * 1024 + o];
            float w2 = W5t[(size_t)(c + 2) * 1024 + o];
            float w3 = W5t[(size_t)(c + 3) * 1024 + o];
            #pragma unroll
            for (int r = 0; r < RSTAGE; ++r) {
                float4 rv = *reinterpret_cast<const float4*>(&rows[r][c]);
                acc[r] += rv.x * w0 + rv.y * w1 + rv.z * w2 + rv.w * w3;
            }
        }
        #pragma unroll
        for (int r = 0; r < RSTAGE; ++r) {
            float v = leaky(acc[r] * s + bo);
            vmax = fmaxf(vmax, v); vsum += v;
        }
    }
    pmax[((size_t)b * 1024 + o) * 32 + nc] = vmax;
    psum[((size_t)b * 1024 + o) * 32 + nc] = vsum;
}

__global__ void pool_reduce_kernel(const float* __restrict__ pmax, const float* __restrict__ psum,
                                   float* __restrict__ f0) {
    int i = blockIdx.x * blockDim.x + threadIdx.x;
    if (i >= NB * 1024) return;
    int b = i >> 10, o = i & 1023;
    float m = -INFINITY, sm = 0.f;
    for (int nc = 0; nc < 32; ++nc) { m = fmaxf(m, pmax[(size_t)i * 32 + nc]); sm += psum[(size_t)i * 32 + nc]; }
    f0[(size_t)b * 2048 + o] = m;
    f0[(size_t)b * 2048 + 1024 + o] = sm * (1.0f / 2048.0f);
}

// ---------------- dense: one thread per (b, o) ----------------
__global__ void dense_kernel(const float* __restrict__ in, const float* __restrict__ W,
                             const float* __restrict__ bl, const float* __restrict__ g,
                             const float* __restrict__ bb, float* __restrict__ out,
                             int In, int Out, int act) {
    int i = blockIdx.x * blockDim.x + threadIdx.x;
    if (i >= NB * Out) return;
    int b = i / Out, o = i - b * Out;
    const float* w = W + (size_t)o * In;
    const float* xv = in + (size_t)b * In;
    float acc = 0.f;
    for (int c = 0; c < In; ++c) acc += xv[c] * w[c];
    acc += bl[o];
    if (act) {
        const float bns = 1.0f / sqrtf(1.0f + 1e-5f);
        acc = leaky(acc * (g[o] * bns) + bb[o]);
    }
    out[i] = acc;
}

extern "C" void kernel_launch(void* const* d_in, const int* in_sizes, int n_in,
                              void* d_out, int out_size, void* d_ws, size_t ws_size,
                              hipStream_t stream) {
    const float* x   = (const float*)d_in[0];
    const float* W1  = (const float*)d_in[2];
    const float* W2  = (const float*)d_in[3];
    const float* W3  = (const float*)d_in[4];
    const float* W4  = (const float*)d_in[5];
    const float* W5  = (const float*)d_in[6];
    const float* Wl1 = (const float*)d_in[7];
    const float* bl1 = (const float*)d_in[8];
    const float* Wl2 = (const float*)d_in[9];
    const float* bl2 = (const float*)d_in[10];
    const float* Wl3 = (const float*)d_in[11];
    const float* bl3 = (const float*)d_in[12];
    const float* g1 = (const float*)d_in[13]; const float* b1 = (const float*)d_in[14];
    const float* g2 = (const float*)d_in[15]; const float* b2 = (const float*)d_in[16];
    const float* g3 = (const float*)d_in[17]; const float* b3 = (const float*)d_in[18];
    const float* g4 = (const float*)d_in[19]; const float* b4 = (const float*)d_in[20];
    const float* g5 = (const float*)d_in[21]; const float* b5 = (const float*)d_in[22];
    const float* g6 = (const float*)d_in[23]; const float* bb6 = (const float*)d_in[24];
    const float* g7 = (const float*)d_in[25]; const float* bb7 = (const float*)d_in[26];

    float* ws = (float*)d_ws;
    size_t off = 0;
    float* CAT = ws + off; off += (size_t)NB * NP * CSTR;
    float* SQ  = ws + off; off += NB * NP;
    int*   IDX = (int*)(ws + off); off += (size_t)NB * NP * KNN;
    float* WYZ1 = ws + off; off += 4 * 128;
    float* WYZ2 = ws + off; off += 68 * 128;
    float* WYZ3 = ws + off; off += 132 * 256;
    float* WYZ4 = ws + off; off += 260 * 512;
    float* W5T = ws + off; off += 520 * 1024;
    float* YZ  = ws + off; off += (size_t)NB * NP * 512;   // 33.5 MB, reused per layer
    // pooling/head buffers alias YZ (temporally disjoint: YZ dead after last combine)
    float* PMAX = YZ;
    float* PSUM = PMAX + (size_t)NB * 1024 * 32;
    float* F0 = PSUM + (size_t)NB * 1024 * 32;
    float* F1 = F0 + NB * 2048;
    float* F2 = F1 + NB * 512;
    (void)off; (void)ws_size; (void)in_sizes; (void)n_in; (void)out_size;

    dim3 b256(256);
    const int M16 = NB * NP / 16;   // 1024 row-blocks

    tx_kernel<<<(NB * NP + 255) / 256, b256, 0, stream>>>(x, CAT);
    buildWyz<<<(4 * 128 + 255) / 256, b256, 0, stream>>>(W1, WYZ1, 64, 3, 4);
    buildWyz<<<(68 * 128 + 255) / 256, b256, 0, stream>>>(W2, WYZ2, 64, 67, 68);
    buildWyz<<<(132 * 256 + 255) / 256, b256, 0, stream>>>(W3, WYZ3, 128, 131, 132);
    buildWyz<<<(260 * 512 + 255) / 256, b256, 0, stream>>>(W4, WYZ4, 256, 259, 260);
    transposeW5<<<(520 * 1024 + 255) / 256, b256, 0, stream>>>(W5, W5T);

    // layer 1: knn on xc (C=4 @0); GEMM over cols [0,4) -> N2=128; combine -> col 4
    sqnorm_kernel<<<(NB * NP + 255) / 256, b256, 0, stream>>>(CAT, 0, 4, SQ);
    knn2_kernel<4><<<NB * NP / 4, b256, 0, stream>>>(CAT, 0, SQ, IDX);
    gemm_yz_kernel<4, 128><<<dim3(M16, 1), 128, 0, stream>>>(CAT, 0, WYZ1, 128, YZ);
    combine_kernel<64><<<NB * NP / 4, b256, 0, stream>>>(YZ, 128, IDX, g1, b1, CAT, 4);
    // layer 2: knn on x1 (C=64 @4); GEMM over cols [0,68); combine -> col 68
    sqnorm_kernel<<<(NB * NP + 255) / 256, b256, 0, stream>>>(CAT, 4, 64, SQ);
    knn2_kernel<64><<<NB * NP / 4, b256, 0, stream>>>(CAT, 4, SQ, IDX);
    gemm_yz_kernel<68, 128><<<dim3(M16, 1), 128, 0, stream>>>(CAT, 0, WYZ2, 128, YZ);
    combine_kernel<64><<<NB * NP / 4, b256, 0, stream>>>(YZ, 128, IDX, g2, b2, CAT, 68);
    // layer 3: knn on x2 (C=64 @68); GEMM over cols [0,132); combine -> col 132
    sqnorm_kernel<<<(NB * NP + 255) / 256, b256, 0, stream>>>(CAT, 68, 64, SQ);
    knn2_kernel<64><<<NB * NP / 4, b256, 0, stream>>>(CAT, 68, SQ, IDX);
    gemm_yz_kernel<132, 256><<<dim3(M16, 1), 256, 0, stream>>>(CAT, 0, WYZ3, 256, YZ);
    combine_kernel<128><<<NB * NP / 2, b256, 0, stream>>>(YZ, 256, IDX, g3, b3, CAT, 132);
    // layer 4: knn on x3 (C=128 @132); GEMM over cols [0,260); combine -> col 260
    sqnorm_kernel<<<(NB * NP + 255) / 256, b256, 0, stream>>>(CAT, 132, 128, SQ);
    knn2_kernel<128><<<NB * NP / 4, b256, 0, stream>>>(CAT, 132, SQ, IDX);
    gemm_yz_kernel<260, 256><<<dim3(M16, 2), 256, 0, stream>>>(CAT, 0, WYZ4, 512, YZ);
    combine_kernel<256><<<NB * NP, b256, 0, stream>>>(YZ, 512, IDX, g4, b4, CAT, 260);

    // W5 + bn + leaky + global max/mean pool
    pool_w5_kernel<<<NB * 4 * 32, b256, 0, stream>>>(CAT, W5T, g5, b5, PMAX, PSUM);
    pool_reduce_kernel<<<(NB * 1024 + 255) / 256, b256, 0, stream>>>(PMAX, PSUM, F0);

    // MLP head
    dense_kernel<<<(NB * 512 + 255) / 256, b256, 0, stream>>>(F0, Wl1, bl1, g6, bb6, F1, 2048, 512, 1);
    dense_kernel<<<(NB * 256 + 255) / 256, b256, 0, stream>>>(F1, Wl2, bl2, g7, bb7, F2, 512, 256, 1);
    dense_kernel<<<(NB * 40 + 255) / 256, b256, 0, stream>>>(F2, Wl3, bl3, nullptr, nullptr,
                                                             (float*)d_out, 256, 40, 0);
}